// Round 4
// baseline (370.155 us; speedup 1.0000x reference)
//
#include <hip/hip_runtime.h>
#include <hip/hip_bf16.h>

// SegmentConv2d: fake-quant-int8 (global for x, per-128-oc-chunk for w) + 3x3 pad1 conv + bias.
// int8 path: quantize to real int8, conv with mfma_i32_16x16x64_i8 (exact int accum),
// scale+bias epilogue.
//
// Shapes: x[8][256][128][128] f32, w[512][256][3][3] f32, bias[512], out[8][512][128][128] f32.
//
// ws layout:
//   [0..255]        : amax[5] (uint bits, atomicMax) + 16B zero area at +64 (OOB redirect)
//   [256 ..)        : qx int8 NHWC  [n][h][w][c]  = 33,554,432 B
//   [256+32M ..)    : qw int8       [r*3+s][oc][c] = 1,179,648 B

typedef int i32x4 __attribute__((ext_vector_type(4)));

__device__ __forceinline__ void llds16(const void* g, void* l) {
    __builtin_amdgcn_global_load_lds(
        (const __attribute__((address_space(1))) void*)g,
        (__attribute__((address_space(3))) void*)l,
        16, 0, 0);
}

__device__ __forceinline__ float f4max(float4 v) {
    return fmaxf(fmaxf(fabsf(v.x), fabsf(v.y)), fmaxf(fabsf(v.z), fabsf(v.w)));
}

// ---------------- amax (x and w merged) ----------------
// Blocks [0,2048): x, 16 independent float4 loads in flight (latency fix).
// Blocks [2048,3200): w, 288 blocks per 128-oc chunk.
__global__ __launch_bounds__(256) void k_amax(const float4* __restrict__ x,
                                              const float4* __restrict__ w4,
                                              unsigned* __restrict__ dst) {
    float m = 0.f;
    unsigned* slot;
    if (blockIdx.x < 2048) {
        int tid = blockIdx.x * 256 + threadIdx.x;
        float4 v[16];
#pragma unroll
        for (int k = 0; k < 16; ++k)
            v[k] = x[(size_t)tid + (size_t)k * 524288];
#pragma unroll
        for (int k = 0; k < 16; ++k) m = fmaxf(m, f4max(v[k]));
        slot = dst;
    } else {
        int b = blockIdx.x - 2048;          // 0..1151
        int chunk = b / 288;
        int tid = (b - chunk * 288) * 256 + threadIdx.x;
        m = f4max(w4[(size_t)chunk * 73728 + tid]);
        slot = dst + 1 + chunk;
    }
    for (int off = 32; off > 0; off >>= 1) m = fmaxf(m, __shfl_xor(m, off, 64));
    if ((threadIdx.x & 63) == 0) atomicMax(slot, __float_as_uint(m));
}

// ---------------- quantize x : NCHW f32 -> NHWC int8 ----------------
// block = one (n,h) row, 256 threads, NO LDS: each thread loads 16 float4 (16
// c-planes x 4 w, all independent -> 16 loads in flight), register-transposes,
// stores 4x uint4 (16 contiguous c bytes each). Scattered 16B stores merge in L2.
__global__ __launch_bounds__(256) void k_quant_x(const float* __restrict__ x,
                                                 signed char* __restrict__ qx,
                                                 const unsigned* __restrict__ amaxb) {
    float inv = 127.0f / fmaxf(__uint_as_float(amaxb[0]), 1e-12f);
    int row = blockIdx.x;                 // n*128 + h
    int n = row >> 7, h = row & 127;
    int t = threadIdx.x;
    int w4 = t & 31, cg = t >> 5;         // w4: float4 slot along w; cg in [0,8)
    const float* base = x + (size_t)n * 256 * 16384 + (size_t)h * 128 + w4 * 4;
#pragma unroll
    for (int pp = 0; pp < 2; ++pp) {
        int c0 = pp * 128 + cg * 16;
        float4 v[16];
#pragma unroll
        for (int j = 0; j < 16; ++j)
            v[j] = *(const float4*)(base + (size_t)(c0 + j) * 16384);
#pragma unroll
        for (int i = 0; i < 4; ++i) {
            unsigned wds[4];
#pragma unroll
            for (int jg = 0; jg < 4; ++jg) {
                unsigned u = 0;
#pragma unroll
                for (int jj = 0; jj < 4; ++jj) {
                    float f = (&v[jg * 4 + jj].x)[i];
                    int q = (int)fminf(fmaxf(rintf(f * inv), -128.f), 127.f);
                    u |= ((unsigned)(q & 255)) << (8 * jj);
                }
                wds[jg] = u;
            }
            *(uint4*)&qx[(size_t)row * 32768 + (size_t)(w4 * 4 + i) * 256 + c0] =
                make_uint4(wds[0], wds[1], wds[2], wds[3]);
        }
    }
}

// ---------------- quantize w : OIHW f32 -> [rs][oc][c] int8 ----------------
__global__ void k_quant_w(const float* __restrict__ wsrc, signed char* __restrict__ qw,
                          const unsigned* __restrict__ amaxb) {
    int idx = blockIdx.x * 256 + threadIdx.x;   // 131072 = 512 blocks
    int oc = idx >> 8, c = idx & 255;
    float inv = 127.0f / fmaxf(__uint_as_float(amaxb[1 + (oc >> 7)]), 1e-12f);
    const float* src = wsrc + (size_t)idx * 9;
    float v[9];
#pragma unroll
    for (int rs = 0; rs < 9; ++rs) v[rs] = src[rs];
#pragma unroll
    for (int rs = 0; rs < 9; ++rs) {
        float qf = fminf(fmaxf(rintf(v[rs] * inv), -128.f), 127.f);
        qw[((size_t)(rs * 512 + oc)) * 256 + c] = (signed char)(int)qf;
    }
}

// ---------------- conv : implicit GEMM with mfma_i32_16x16x64_i8 ----------------
// grid 4096 (bijective XCD swizzle: each XCD owns one image n), block 256 (4 waves).
// Block tile: 64 oc x 256 px (2 output rows). Wave (rowsel=wid>>1, whalf=wid&1) owns
// 64oc x 64px. 4 phases over cb (64 c each); per phase: ALL 4 input rows + ALL 9 (r,s)
// weight planes staged -> 144 MFMA/wave. DOUBLE-BUFFERED (140 KB LDS, 1 block/CU):
// next phase's global_load_lds issued BEFORE the MFMA cluster; __syncthreads' implicit
// vmcnt(0) drain then lands after ~2940 cy of MFMA has hidden the ~1200 cy staging.
// Fragment LDS reads XOR-swizzled (8-way -> 2-way) via permuted GLOBAL source q4.
__global__ __launch_bounds__(256) void k_conv(
    const signed char* __restrict__ qx, const signed char* __restrict__ qw,
    const signed char* __restrict__ zb, const unsigned* __restrict__ amaxb,
    const float* __restrict__ bias, float* __restrict__ out) {
    __shared__ __align__(16) signed char xs[2][4 * 8320];    // 2 x 33280 B
    __shared__ __align__(16) signed char wt[2][9 * 4096];    // 2 x 36864 B
    int orig = blockIdx.x;                      // 0..4095, nwg % 8 == 0
    int wgid = (orig & 7) * 512 + (orig >> 3);  // bijective XCD swizzle
    int rowpair = wgid >> 3, ocg = wgid & 7;
    int n = rowpair >> 6;                       // 64 rowpairs per image
    int h0 = (rowpair & 63) * 2;
    int t = threadIdx.x, wid = t >> 6, lane = t & 63;
    int p = lane & 15, hi = lane >> 4;
    int rowsel = wid >> 1, whalf = wid & 1;

    i32x4 acc[4][4] = {};

    auto stage = [&](int cb, int buf) {
        // xs: 4 rows x 130 w x 4 q4 = 2080 x 16B, lane-linear LDS dest
#pragma unroll
        for (int i = 0; i < 9; ++i) {
            int idx = t + i * 256;
            if (idx < 2080) {
                int rowk = idx / 520;
                int j = idx - rowk * 520;
                int wr = j >> 2, q4 = j & 3;
                int wg = wr - 1;
                int hh = h0 - 1 + rowk;
                int q4s = q4 ^ ((wr >> 1) & 3);
                const signed char* src = (hh >= 0 && hh < 128 && wg >= 0 && wg < 128)
                    ? qx + (size_t)(n * 128 + hh) * 32768 + wg * 256 + cb * 64 + q4s * 16
                    : zb;
                llds16(src, &xs[buf][0] + (size_t)(i * 256 + wid * 64) * 16);
            }
        }
        // wt: 9 rs x 64 oc x 4 q4 = 2304 x 16B
#pragma unroll
        for (int i = 0; i < 9; ++i) {
            int idx = t + i * 256;
            int rs = idx >> 8, rem = idx & 255;
            int oc = rem >> 2, q4 = rem & 3;
            int q4s = q4 ^ ((oc >> 1) & 3);
            const signed char* src = qw
                + (size_t)(rs * 512 + ocg * 64 + oc) * 256 + cb * 64 + q4s * 16;
            llds16(src, &wt[buf][0] + (size_t)(i * 256 + wid * 64) * 16);
        }
    };

    auto compute = [&](int buf) {
#pragma unroll
        for (int r = 0; r < 3; ++r) {
            int rowk = r + rowsel;
#pragma unroll
            for (int s = 0; s < 3; ++s) {
                i32x4 a[4], b[4];
#pragma unroll
                for (int mf = 0; mf < 4; ++mf) {
                    int ocr = mf * 16 + p;
                    a[mf] = *(const i32x4*)&wt[buf][(r * 3 + s) * 4096 + ocr * 64
                                               + ((hi ^ ((ocr >> 1) & 3)) << 4)];
                }
#pragma unroll
                for (int nf = 0; nf < 4; ++nf) {
                    int wrow = whalf * 64 + nf * 16 + p + s;
                    b[nf] = *(const i32x4*)&xs[buf][rowk * 8320 + wrow * 64
                                               + ((hi ^ ((wrow >> 1) & 3)) << 4)];
                }
#pragma unroll
                for (int mf = 0; mf < 4; ++mf)
#pragma unroll
                    for (int nf = 0; nf < 4; ++nf)
                        acc[mf][nf] = __builtin_amdgcn_mfma_i32_16x16x64_i8(
                            a[mf], b[nf], acc[mf][nf], 0, 0, 0);
            }
        }
    };

    stage(0, 0);
    __syncthreads();                      // compiler drains vmcnt(0) here
#pragma unroll
    for (int cb = 0; cb < 4; ++cb) {
        if (cb < 3) stage(cb + 1, (cb + 1) & 1);   // async into other buffer
        compute(cb & 1);                           // hides staging latency
        __syncthreads();                           // reads done + stage landed
    }

    float sx = fmaxf(__uint_as_float(amaxb[0]), 1e-12f) / 127.0f;
    float sw = fmaxf(__uint_as_float(amaxb[1 + (ocg >> 1)]), 1e-12f) / 127.0f;
    float sc = sx * sw;
    int h = h0 + rowsel;
#pragma unroll
    for (int mf = 0; mf < 4; ++mf)
#pragma unroll
        for (int nf = 0; nf < 4; ++nf)
#pragma unroll
            for (int j = 0; j < 4; ++j) {
                int oc = ocg * 64 + mf * 16 + hi * 4 + j;
                int px = whalf * 64 + nf * 16 + p;
                out[((size_t)(n * 512 + oc) * 128 + h) * 128 + px] =
                    (float)acc[mf][nf][j] * sc + bias[oc];
            }
}

extern "C" void kernel_launch(void* const* d_in, const int* in_sizes, int n_in,
                              void* d_out, int out_size, void* d_ws, size_t ws_size,
                              hipStream_t stream) {
    const float* x    = (const float*)d_in[0];
    const float* wgt  = (const float*)d_in[1];
    const float* bias = (const float*)d_in[2];
    float* out = (float*)d_out;

    unsigned* amaxb = (unsigned*)d_ws;
    signed char* qx = (signed char*)d_ws + 256;
    signed char* qw = (signed char*)d_ws + 256 + 33554432;
    const signed char* zb = (const signed char*)d_ws + 64;   // 16B zeros for OOB redirect

    hipMemsetAsync(d_ws, 0, 256, stream);   // amax slots + zero area (graph-capturable)

    k_amax<<<3200, 256, 0, stream>>>((const float4*)x, (const float4*)wgt, amaxb);
    k_quant_x<<<1024, 256, 0, stream>>>(x, qx, amaxb);
    k_quant_w<<<512, 256, 0, stream>>>(wgt, qw, amaxb);
    k_conv<<<dim3(4096), 256, 0, stream>>>(qx, qw, zb, amaxb, bias, out);
}